// Round 5
// baseline (491.738 us; speedup 1.0000x reference)
//
#include <hip/hip_runtime.h>
#include <hip/hip_bf16.h>

typedef unsigned short u16;
typedef unsigned int u32;
typedef __bf16 bf16x8 __attribute__((ext_vector_type(8)));
typedef float f32x4 __attribute__((ext_vector_type(4)));

#define N_ 32
#define D_ 512
#define P_ 3136   // 56*56
#define K_ 64
#define TILES_P 49
#define NDP (D_ * P_)

// ---- workspace layout (bytes) ----
// wbf   : bf16 conv_w [64][512]            @ 0
// a_ws  : bf16 a' [32][64][3136]           @ 65536
// a_sum : f32 [32][64]                     @ 12910592
// agg   : f32 [7][32][64][512]             @ 12918784
// rowsq : f32 [32][64]                     @ 42278912
// xbf   : bf16 x [32][512][3136]           @ 42287104
// x_t   : bf16 x^T [32][3136][512]         @ 145047552
// psum  : f32 [32][3136]                   @ 247808000

__device__ __forceinline__ u16 f2bf(float f) {       // RNE float->bf16 bits
  u32 u = __float_as_uint(f);
  return (u16)((u + 0x7fffu + ((u >> 16) & 1u)) >> 16);
}
__device__ __forceinline__ u32 pack2(float a, float b) {
  return (u32)f2bf(a) | ((u32)f2bf(b) << 16);
}

// -------- KW: conv_w fp32 -> bf16 --------
__global__ __launch_bounds__(256) void kw_kernel(const float* __restrict__ w,
                                                 u16* __restrict__ wbf) {
  int i = blockIdx.x * 256 + threadIdx.x;
  float4 v = ((const float4*)w)[i];
  ((uint2*)wbf)[i] = make_uint2(pack2(v.x, v.y), pack2(v.z, v.w));
}

// -------- T_bf: x fp32 -> bf16, same [n][d][px] layout (pure stream) --------
__global__ __launch_bounds__(256) void tbf_kernel(const float* __restrict__ x,
                                                  u16* __restrict__ xbf) {
  const int nf4 = (N_ * NDP) / 4;       // 12,845,056 float4s
  for (int i = blockIdx.x * 256 + threadIdx.x; i < nf4; i += 2048 * 256) {
    float4 v = ((const float4*)x)[i];
    ((uint2*)xbf)[i] = make_uint2(pack2(v.x, v.y), pack2(v.z, v.w));
  }
}

// -------- T_t: gather-transpose xbf [d][px] -> x_t [px][d]; per-px sumsq ----
// block = (n, 64-px tile); lane (w,q,c): pixel w*16+c, d-runs it*32+q*8.
// 8 scalar u16 loads (L3-warm) -> one 16B store per fragment. No LDS.
__global__ __launch_bounds__(256) void tt_kernel(const u16* __restrict__ xbf,
                                                 u16* __restrict__ xt,
                                                 float* __restrict__ psum) {
  const int bid = blockIdx.x;
  const int n = bid / TILES_P;
  const int tile = bid - n * TILES_P;
  const int p0 = tile * 64;
  const int t = threadIdx.x;
  const int lane = t & 63;
  const int w = t >> 6;
  const int c = lane & 15;
  const int q = lane >> 4;
  const int gpx = p0 + w * 16 + c;

  const u16* src = xbf + (size_t)n * NDP + gpx;
  u16* dst = xt + ((size_t)n * P_ + gpx) * D_;
  float s0 = 0.f, s1 = 0.f;
#pragma unroll
  for (int it = 0; it < 16; ++it) {
    const u16* sp = src + (size_t)(it * 32 + q * 8) * P_;
    u32 u[4];
#pragma unroll
    for (int j = 0; j < 4; ++j) {
      u32 lo = sp[(size_t)(2 * j) * P_];
      u32 hi = sp[(size_t)(2 * j + 1) * P_];
      u[j] = lo | (hi << 16);
      float f0 = __uint_as_float(lo << 16);
      float f1 = __uint_as_float(hi << 16);
      s0 += f0 * f0;
      s1 += f1 * f1;
    }
    *(uint4*)(dst + it * 32 + q * 8) = make_uint4(u[0], u[1], u[2], u[3]);
  }
  float ssq = s0 + s1;
  ssq += __shfl_xor(ssq, 16);
  ssq += __shfl_xor(ssq, 32);
  if (q == 0) psum[n * P_ + gpx] = ssq;
}

// -------- K1: logits GEMM + softmax -> a' (bf16), a_sum --------
// Both operands fragment-contiguous from global (x_t rows, wbf rows).
// No LDS in K-loop, no conversions, 2-deep prefetch.
__global__ __launch_bounds__(256) void k1_kernel(const u16* __restrict__ xt,
                                                 const u16* __restrict__ wbf,
                                                 const float* __restrict__ psum,
                                                 u16* __restrict__ a_ws,
                                                 float* __restrict__ a_sum) {
  __shared__ float a_stage[64][65];
  __shared__ float invn_s[64];
  const int t = threadIdx.x;
  const int bid = blockIdx.x;
  const int n = bid / TILES_P;
  const int tile = bid - n * TILES_P;
  const int p0 = tile * 64;
  const int lane = t & 63;
  const int w = t >> 6;
  const int c = lane & 15;
  const int q = lane >> 4;
  const int rp = w * 16 + c;

  if (t < 64)
    invn_s[t] = 1.f / fmaxf(sqrtf(psum[n * P_ + p0 + t]), 1e-12f);
  const float inv_p = 1.f / fmaxf(sqrtf(psum[n * P_ + p0 + rp]), 1e-12f);

  const bf16x8* brow = (const bf16x8*)(xt + ((size_t)n * P_ + p0 + rp) * D_);
  const bf16x8* wrow = (const bf16x8*)wbf;

  f32x4 acc[4];
#pragma unroll
  for (int m = 0; m < 4; ++m) acc[m] = (f32x4){0.f, 0.f, 0.f, 0.f};

  bf16x8 pb[2];
  bf16x8 pa[2][4];
  pb[0] = brow[q];
  pb[1] = brow[4 + q];
#pragma unroll
  for (int m = 0; m < 4; ++m) {
    pa[0][m] = wrow[(m * 16 + c) * 64 + q];
    pa[1][m] = wrow[(m * 16 + c) * 64 + 4 + q];
  }
#pragma unroll
  for (int s = 0; s < 16; ++s) {
    const int cur = s & 1;
    bf16x8 bfr = pb[cur];
    bf16x8 a0 = pa[cur][0], a1 = pa[cur][1], a2 = pa[cur][2], a3 = pa[cur][3];
    if (s < 14) {
      pb[cur] = brow[(s + 2) * 4 + q];
#pragma unroll
      for (int m = 0; m < 4; ++m)
        pa[cur][m] = wrow[(m * 16 + c) * 64 + (s + 2) * 4 + q];
    }
    acc[0] = __builtin_amdgcn_mfma_f32_16x16x32_bf16(a0, bfr, acc[0], 0, 0, 0);
    acc[1] = __builtin_amdgcn_mfma_f32_16x16x32_bf16(a1, bfr, acc[1], 0, 0, 0);
    acc[2] = __builtin_amdgcn_mfma_f32_16x16x32_bf16(a2, bfr, acc[2], 0, 0, 0);
    acc[3] = __builtin_amdgcn_mfma_f32_16x16x32_bf16(a3, bfr, acc[3], 0, 0, 0);
  }

  // softmax over k: lanes q + regs (m,r) hold all 64 k of pixel rp
  float sc[4][4];
  float lmax = -3.0e38f;
#pragma unroll
  for (int m = 0; m < 4; ++m)
#pragma unroll
    for (int r = 0; r < 4; ++r) {
      float val = acc[m][r] * inv_p;
      sc[m][r] = val;
      lmax = fmaxf(lmax, val);
    }
  lmax = fmaxf(lmax, __shfl_xor(lmax, 16));
  lmax = fmaxf(lmax, __shfl_xor(lmax, 32));
  float lsum = 0.f;
#pragma unroll
  for (int m = 0; m < 4; ++m)
#pragma unroll
    for (int r = 0; r < 4; ++r) {
      float e = __expf(sc[m][r] - lmax);
      sc[m][r] = e;
      lsum += e;
    }
  lsum += __shfl_xor(lsum, 16);
  lsum += __shfl_xor(lsum, 32);
  const float rs = 1.f / lsum;
#pragma unroll
  for (int m = 0; m < 4; ++m)
#pragma unroll
    for (int r = 0; r < 4; ++r)
      a_stage[m * 16 + q * 4 + r][rp] = sc[m][r] * rs;   // a (pre inv_n)
  __syncthreads();

  // write a' = a*inv_p as bf16 (coalesced 32B/thread) + a_sum atomics
  {
    const int k = t >> 2, pc = t & 3;
    float ssum = 0.f;
    u32 u[8];
#pragma unroll
    for (int jj = 0; jj < 8; ++jj) {
      int p = pc * 16 + jj * 2;
      float a0 = a_stage[k][p], a1 = a_stage[k][p + 1];
      ssum += a0 + a1;
      u[jj] = (u32)f2bf(a0 * invn_s[p]) | ((u32)f2bf(a1 * invn_s[p + 1]) << 16);
    }
    u16* dst = a_ws + (size_t)n * (K_ * P_) + k * P_ + p0 + pc * 16;
    ((uint4*)dst)[0] = make_uint4(u[0], u[1], u[2], u[3]);
    ((uint4*)dst)[1] = make_uint4(u[4], u[5], u[6], u[7]);
    ssum += __shfl_xor(ssum, 1);
    ssum += __shfl_xor(ssum, 2);
    if ((t & 3) == 0) atomicAdd(&a_sum[n * 64 + k], ssum);
  }
}

// -------- K2: agg[k,d] = sum_p a'[k,p] * xbf[d,p] --------
// Both operands bf16, fragment-contiguous from global. No LDS, no barriers.
// The 8 dblk-blocks sharing one (n,pp) a'-slab get ids differing by 8
// (same XCD under round-robin dispatch) for L2 reuse.
__global__ __launch_bounds__(256) void k2_kernel(const u16* __restrict__ xbf,
                                                 const u16* __restrict__ a_ws,
                                                 float* __restrict__ agg) {
  const int b = blockIdx.x;             // 1792
  const int dblk = (b >> 3) & 7;
  const int npp = (b >> 6) * 8 + (b & 7);
  const int n = npp / 7;
  const int pp = npp - n * 7;
  const int t = threadIdx.x;
  const int lane = t & 63, w = t >> 6;
  const int c = lane & 15, q = lane >> 4;
  const int d0 = dblk * 64 + w * 16;

  f32x4 acc[4];
#pragma unroll
  for (int m = 0; m < 4; ++m) acc[m] = (f32x4){0.f, 0.f, 0.f, 0.f};

  const u16* ab = a_ws + (size_t)n * (K_ * P_) + pp * 448 + q * 8;
  const u16* xb = xbf + ((size_t)n * D_ + d0 + c) * P_ + pp * 448 + q * 8;

  bf16x8 pb[2];
  bf16x8 pa[2][4];
#pragma unroll
  for (int k2 = 0; k2 < 2; ++k2) {
    pb[k2] = *(const bf16x8*)(xb + k2 * 32);
#pragma unroll
    for (int m = 0; m < 4; ++m)
      pa[k2][m] = *(const bf16x8*)(ab + (size_t)(m * 16 + c) * P_ + k2 * 32);
  }
#pragma unroll
  for (int it = 0; it < 14; ++it) {
    const int cur = it & 1;
    bf16x8 bfr = pb[cur];
    bf16x8 a0 = pa[cur][0], a1 = pa[cur][1], a2 = pa[cur][2], a3 = pa[cur][3];
    if (it < 12) {
      pb[cur] = *(const bf16x8*)(xb + (it + 2) * 32);
#pragma unroll
      for (int m = 0; m < 4; ++m)
        pa[cur][m] = *(const bf16x8*)(ab + (size_t)(m * 16 + c) * P_ + (it + 2) * 32);
    }
    acc[0] = __builtin_amdgcn_mfma_f32_16x16x32_bf16(a0, bfr, acc[0], 0, 0, 0);
    acc[1] = __builtin_amdgcn_mfma_f32_16x16x32_bf16(a1, bfr, acc[1], 0, 0, 0);
    acc[2] = __builtin_amdgcn_mfma_f32_16x16x32_bf16(a2, bfr, acc[2], 0, 0, 0);
    acc[3] = __builtin_amdgcn_mfma_f32_16x16x32_bf16(a3, bfr, acc[3], 0, 0, 0);
  }
  float* ob = agg + ((size_t)pp * 32 + n) * (K_ * D_);
#pragma unroll
  for (int m = 0; m < 4; ++m)
#pragma unroll
    for (int r = 0; r < 4; ++r)
      ob[(m * 16 + q * 4 + r) * D_ + d0 + c] = acc[m][r];
}

// -------- K3a: vlad = sum_pp agg[pp] - a_sum*c ; per-row sumsq --------
// 512 blocks x 4 waves; wave w owns row k = kg*4+w (independent, shfl-only).
__global__ __launch_bounds__(256) void k3a_kernel(const float* __restrict__ agg,
                                                  const float* __restrict__ a_sum,
                                                  const float* __restrict__ cent,
                                                  float* __restrict__ out,
                                                  float* __restrict__ rowsq) {
  const int b = blockIdx.x;             // n*16 + kg
  const int n = b >> 4, kg = b & 15;
  const int t = threadIdx.x;
  const int lane = t & 63, w = t >> 6;
  const int k = kg * 4 + w;
  const float* ab = agg + ((size_t)n * 64 + k) * 512 + lane * 8;
  float v[8];
#pragma unroll
  for (int j = 0; j < 8; ++j) v[j] = 0.f;
#pragma unroll
  for (int pp = 0; pp < 7; ++pp) {
    const float4* p4 = (const float4*)(ab + (size_t)pp * 32 * (K_ * D_));
    float4 r0 = p4[0], r1 = p4[1];
    v[0] += r0.x; v[1] += r0.y; v[2] += r0.z; v[3] += r0.w;
    v[4] += r1.x; v[5] += r1.y; v[6] += r1.z; v[7] += r1.w;
  }
  const float asum = a_sum[n * 64 + k];
  const float4* c4 = (const float4*)(cent + k * 512 + lane * 8);
  float4 c0 = c4[0], c1 = c4[1];
  v[0] -= asum * c0.x; v[1] -= asum * c0.y; v[2] -= asum * c0.z; v[3] -= asum * c0.w;
  v[4] -= asum * c1.x; v[5] -= asum * c1.y; v[6] -= asum * c1.z; v[7] -= asum * c1.w;
  float ssq = 0.f;
#pragma unroll
  for (int j = 0; j < 8; ++j) ssq += v[j] * v[j];
  ssq += __shfl_xor(ssq, 1);  ssq += __shfl_xor(ssq, 2);  ssq += __shfl_xor(ssq, 4);
  ssq += __shfl_xor(ssq, 8);  ssq += __shfl_xor(ssq, 16); ssq += __shfl_xor(ssq, 32);
  float4* o4 = (float4*)(out + (size_t)n * 32768 + k * 512 + lane * 8);
  o4[0] = make_float4(v[0], v[1], v[2], v[3]);
  o4[1] = make_float4(v[4], v[5], v[6], v[7]);
  if (lane == 0) rowsq[n * 64 + k] = ssq;
}

// -------- K3b: intra + global normalize (scale in place) --------
__global__ __launch_bounds__(256) void k3b_kernel(const float* __restrict__ rowsq,
                                                  float* __restrict__ out) {
  __shared__ float invr_s[64];
  __shared__ float gi_s;
  const int n = blockIdx.x >> 3;
  const int seg = blockIdx.x & 7;
  const int t = threadIdx.x;
  if (t < 64) {
    float r = rowsq[n * 64 + t];
    float ri = 1.f / fmaxf(sqrtf(r), 1e-12f);
    invr_s[t] = ri;
    float g = r * ri * ri;
    g += __shfl_xor(g, 1); g += __shfl_xor(g, 2); g += __shfl_xor(g, 4);
    g += __shfl_xor(g, 8); g += __shfl_xor(g, 16); g += __shfl_xor(g, 32);
    if (t == 0) gi_s = 1.f / fmaxf(sqrtf(g), 1e-12f);
  }
  __syncthreads();
  const int e0 = seg * 4096 + t * 16;
  const float sc = invr_s[e0 >> 9] * gi_s;
  float4* o4 = (float4*)(out + (size_t)n * 32768 + e0);
#pragma unroll
  for (int i = 0; i < 4; ++i) {
    float4 vv = o4[i];
    vv.x *= sc; vv.y *= sc; vv.z *= sc; vv.w *= sc;
    o4[i] = vv;
  }
}

extern "C" void kernel_launch(void* const* d_in, const int* in_sizes, int n_in,
                              void* d_out, int out_size, void* d_ws, size_t ws_size,
                              hipStream_t stream) {
  (void)in_sizes; (void)n_in; (void)out_size; (void)ws_size;
  const float* x    = (const float*)d_in[0];
  const float* cw   = (const float*)d_in[1];
  const float* cent = (const float*)d_in[2];
  float* out = (float*)d_out;
  char* ws = (char*)d_ws;
  u16*   wbf   = (u16*)(ws);
  u16*   a_ws  = (u16*)(ws + 65536);
  float* a_sum = (float*)(ws + 12910592);
  float* agg   = (float*)(ws + 12918784);
  float* rowsq = (float*)(ws + 42278912);
  u16*   xbf   = (u16*)(ws + 42287104);
  u16*   x_t   = (u16*)(ws + 145047552);
  float* psum  = (float*)(ws + 247808000);

  hipMemsetAsync(a_sum, 0, 64 * 32 * sizeof(float), stream);
  kw_kernel<<<32, 256, 0, stream>>>(cw, wbf);
  tbf_kernel<<<2048, 256, 0, stream>>>(x, xbf);
  tt_kernel<<<32 * TILES_P, 256, 0, stream>>>(xbf, x_t, psum);
  k1_kernel<<<32 * TILES_P, 256, 0, stream>>>(x_t, wbf, psum, a_ws, a_sum);
  k2_kernel<<<1792, 256, 0, stream>>>(xbf, a_ws, agg);
  k3a_kernel<<<512, 256, 0, stream>>>(agg, a_sum, cent, out, rowsq);
  k3b_kernel<<<256, 256, 0, stream>>>(rowsq, out);
}

// Round 7
// 368.413 us; speedup vs baseline: 1.3347x; 1.3347x over previous
//
#include <hip/hip_runtime.h>
#include <hip/hip_bf16.h>

typedef unsigned short u16;
typedef unsigned int u32;
typedef __bf16 bf16x8 __attribute__((ext_vector_type(8)));
typedef float f32x4 __attribute__((ext_vector_type(4)));

#define N_ 32
#define D_ 512
#define P_ 3136   // 56*56
#define K_ 64
#define NDP (D_ * P_)

// ---- workspace layout (bytes) ----
// wbf   : bf16 conv_w [64][512]            @ 0        (65536)
// a_sum : f32 [32][64]                     @ 65536    (8192)
// agg   : f32 [8][32][64][512]             @ 73728    (33554432)
// rowsq : f32 [32][64]                     @ 33628160 (8192)

__device__ __forceinline__ u16 f2bf(float f) {       // RNE float->bf16 bits
  u32 u = __float_as_uint(f);
  return (u16)((u + 0x7fffu + ((u >> 16) & 1u)) >> 16);
}
__device__ __forceinline__ u32 pack2(float a, float b) {
  return (u32)f2bf(a) | ((u32)f2bf(b) << 16);
}

// -------- KW: conv_w fp32 -> bf16 (64KB, L2-resident) --------
__global__ __launch_bounds__(256) void kw_kernel(const float* __restrict__ w,
                                                 u16* __restrict__ wbf) {
  int i = blockIdx.x * 256 + threadIdx.x;
  float4 v = ((const float4*)w)[i];
  ((uint2*)wbf)[i] = make_uint2(pack2(v.x, v.y), pack2(v.z, v.w));
}

// -------- F: fused  stage -> GEMM1 -> softmax -> GEMM2-accumulate --------
// block = (n, slab of 6-7 64-px tiles). 1 block/CU, 156KB LDS.
// f32 image: byte(d,px) = d*256 + (((px>>2) ^ (d&7))<<4) + (px&3)*4
//   (XOR applied on the GLOBAL source address; LDS dest stays linear for
//    global_load_lds; same involution on the read side — rule #21.)
// a image (bf16): byte(k,px) = k*128 + (((px>>3) ^ (k&7))<<4) + (px&7)*2
// GEMM2: waves split the d-range (wave w owns d in [w*128, w*128+128)),
//   so each wave reads only its 32KB d-slice + the 8KB a'-image from LDS.
__global__ __launch_bounds__(256, 1) void f_kernel(const float* __restrict__ x,
                                                   const u16* __restrict__ wbf,
                                                   float* __restrict__ agg,
                                                   float* __restrict__ a_sum) {
  __shared__ __align__(16) char xbuf[131072];    // f32 [512 d][64 px] swizzled
  __shared__ float a_stage[64][65];
  __shared__ float invn_s[64];
  __shared__ __align__(16) char a_bf[8192];      // bf16 a' [64 k][64 px] swizzled

  const int t = threadIdx.x;
  const int lane = t & 63;
  const int w = t >> 6;
  const int c = lane & 15;
  const int q = lane >> 4;
  const int b = blockIdx.x;
  const int n = b >> 3;
  const int s = b & 7;
  const int tile0 = (s == 0) ? 0 : 7 + (s - 1) * 6;
  const int ntl = (s == 0) ? 7 : 6;
  const int rp = w * 16 + c;            // pixel this lane serves in GEMM1/softmax
  const int rpc = rp >> 2;
  const int rpo = (rp & 3) * 4;
  const int c7 = c & 7;

  const bf16x8* wrow = (const bf16x8*)wbf;
  const char* xgb = (const char*)(x + (size_t)n * NDP);

  f32x4 acc2[4][8];                     // GEMM2 acc: all 64 k x d-slice w
#pragma unroll
  for (int m = 0; m < 4; ++m)
#pragma unroll
    for (int i = 0; i < 8; ++i) acc2[m][i] = (f32x4){0.f, 0.f, 0.f, 0.f};
  float ssum_acc = 0.f;

  for (int tt = 0; tt < ntl; ++tt) {
    const int p0 = (tile0 + tt) * 64;

    // ---- stage: 32 global_load_lds x 16B per wave; pre-swizzled source ----
#pragma unroll
    for (int i = 0; i < 32; ++i) {
      const int d = w * 128 + i * 4 + q;            // 4 d-rows per instr
      const char* src = xgb + ((size_t)d * P_ + p0) * 4 + ((c ^ (d & 7)) << 4);
      __builtin_amdgcn_global_load_lds(
          (const __attribute__((address_space(1))) void*)src,
          (__attribute__((address_space(3))) void*)(xbuf + w * 32768 + i * 1024),
          16, 0, 0);
    }
    __syncthreads();                    // compiler drains vmcnt before barrier

    // ---- GEMM1: logits[k][rp] over d; sumsq rides along ----
    f32x4 acc[4];
#pragma unroll
    for (int m = 0; m < 4; ++m) acc[m] = (f32x4){0.f, 0.f, 0.f, 0.f};
    float sumsq = 0.f;
    bf16x8 pa[2][4];
#pragma unroll
    for (int m = 0; m < 4; ++m) {
      pa[0][m] = wrow[(m * 16 + c) * 64 + q];
      pa[1][m] = wrow[(m * 16 + c) * 64 + 4 + q];
    }
    float vc[8];
#pragma unroll
    for (int j = 0; j < 8; ++j)
      vc[j] = *(const float*)(xbuf + ((q * 8 + j) << 8) + ((rpc ^ j) << 4) + rpo);
#pragma unroll
    for (int st = 0; st < 16; ++st) {
      float vn[8];
      if (st < 15) {
#pragma unroll
        for (int j = 0; j < 8; ++j)
          vn[j] = *(const float*)(xbuf + (((st + 1) * 32 + q * 8 + j) << 8) +
                                  ((rpc ^ j) << 4) + rpo);
      }
      bf16x8 bfr;
#pragma unroll
      for (int j = 0; j < 8; ++j) {
        sumsq += vc[j] * vc[j];
        bfr[j] = (__bf16)vc[j];
      }
      bf16x8 nf[4];
      if (st < 14) {
#pragma unroll
        for (int m = 0; m < 4; ++m)
          nf[m] = wrow[(m * 16 + c) * 64 + (st + 2) * 4 + q];
      }
#pragma unroll
      for (int m = 0; m < 4; ++m)
        acc[m] = __builtin_amdgcn_mfma_f32_16x16x32_bf16(pa[st & 1][m], bfr, acc[m], 0, 0, 0);
      if (st < 14) {
#pragma unroll
        for (int m = 0; m < 4; ++m) pa[st & 1][m] = nf[m];
      }
      if (st < 15) {
#pragma unroll
        for (int j = 0; j < 8; ++j) vc[j] = vn[j];
      }
    }

    // per-pixel inv-norm (fp32-exact sumsq), reduce over lane bits 4,5
    sumsq += __shfl_xor(sumsq, 16);
    sumsq += __shfl_xor(sumsq, 32);
    const float inv_p = 1.f / fmaxf(sqrtf(sumsq), 1e-12f);
    if (q == 0) invn_s[rp] = inv_p;

    // ---- softmax over k (lanes q + regs m,r hold all 64 k of pixel rp) ----
    float sc[4][4];
    float lmax = -3.0e38f;
#pragma unroll
    for (int m = 0; m < 4; ++m)
#pragma unroll
      for (int r = 0; r < 4; ++r) {
        float val = acc[m][r] * inv_p;
        sc[m][r] = val;
        lmax = fmaxf(lmax, val);
      }
    lmax = fmaxf(lmax, __shfl_xor(lmax, 16));
    lmax = fmaxf(lmax, __shfl_xor(lmax, 32));
    float lsum = 0.f;
#pragma unroll
    for (int m = 0; m < 4; ++m)
#pragma unroll
      for (int r = 0; r < 4; ++r) {
        float e = __expf(sc[m][r] - lmax);
        sc[m][r] = e;
        lsum += e;
      }
    lsum += __shfl_xor(lsum, 16);
    lsum += __shfl_xor(lsum, 32);
    const float rs = 1.f / lsum;
#pragma unroll
    for (int m = 0; m < 4; ++m)
#pragma unroll
      for (int r = 0; r < 4; ++r)
        a_stage[m * 16 + q * 4 + r][rp] = sc[m][r] * rs;   // a (pre inv_n)
    __syncthreads();

    // ---- a' = a*inv_n -> bf16 LDS image (swizzled) + a_sum partial ----
    {
      const int k = t >> 2, pc4 = t & 3;
      float ssum = 0.f;
      u32 u[8];
#pragma unroll
      for (int jj = 0; jj < 8; ++jj) {
        int p = pc4 * 16 + jj * 2;
        float a0 = a_stage[k][p], a1 = a_stage[k][p + 1];
        ssum += a0 + a1;
        u[jj] = (u32)f2bf(a0 * invn_s[p]) | ((u32)f2bf(a1 * invn_s[p + 1]) << 16);
      }
      *(uint4*)(a_bf + k * 128 + (((pc4 * 2) ^ (k & 7)) << 4)) =
          make_uint4(u[0], u[1], u[2], u[3]);
      *(uint4*)(a_bf + k * 128 + (((pc4 * 2 + 1) ^ (k & 7)) << 4)) =
          make_uint4(u[4], u[5], u[6], u[7]);
      ssum_acc += ssum;
    }
    __syncthreads();

    // ---- GEMM2: agg[k, d in wave-w slice] += a'[k,p] * x[d,p] ----
#pragma unroll
    for (int st = 0; st < 2; ++st) {
      bf16x8 afr[4];
#pragma unroll
      for (int m = 0; m < 4; ++m)       // (m*16+c)&7 == c7
        afr[m] = *(const bf16x8*)(a_bf + (m * 16 + c) * 128 +
                                  (((st * 4 + q) ^ c7) << 4));
      const int pc0 = st * 8 + q * 2;
#pragma unroll
      for (int nt = 0; nt < 8; ++nt) {
        const int d = w * 128 + nt * 16 + c;        // d&7 == c7
        f32x4 b0 = *(const f32x4*)(xbuf + (d << 8) + ((pc0 ^ c7) << 4));
        f32x4 b1 = *(const f32x4*)(xbuf + (d << 8) + (((pc0 + 1) ^ c7) << 4));
        bf16x8 bfr;
#pragma unroll
        for (int i4 = 0; i4 < 4; ++i4) {
          bfr[i4] = (__bf16)b0[i4];
          bfr[4 + i4] = (__bf16)b1[i4];
        }
#pragma unroll
        for (int m = 0; m < 4; ++m)
          acc2[m][nt] = __builtin_amdgcn_mfma_f32_16x16x32_bf16(afr[m], bfr, acc2[m][nt], 0, 0, 0);
      }
    }
    __syncthreads();                    // xbuf/a_bf free for next tile
  }

  // ---- epilogue: write slab partial + a_sum atomics ----
  float* ob = agg + ((size_t)s * 32 + n) * (K_ * D_);
#pragma unroll
  for (int m = 0; m < 4; ++m)
#pragma unroll
    for (int nt = 0; nt < 8; ++nt)
#pragma unroll
      for (int r = 0; r < 4; ++r)
        ob[(m * 16 + q * 4 + r) * D_ + w * 128 + nt * 16 + c] = acc2[m][nt][r];
  ssum_acc += __shfl_xor(ssum_acc, 1);
  ssum_acc += __shfl_xor(ssum_acc, 2);
  if ((t & 3) == 0) atomicAdd(&a_sum[n * 64 + (t >> 2)], ssum_acc);
}

// -------- K3a: vlad = sum_s agg[s] - a_sum*c ; per-row sumsq --------
// 512 blocks x 4 waves; wave w owns row k = kg*4+w.
__global__ __launch_bounds__(256) void k3a_kernel(const float* __restrict__ agg,
                                                  const float* __restrict__ a_sum,
                                                  const float* __restrict__ cent,
                                                  float* __restrict__ out,
                                                  float* __restrict__ rowsq) {
  const int b = blockIdx.x;             // n*16 + kg
  const int n = b >> 4, kg = b & 15;
  const int t = threadIdx.x;
  const int lane = t & 63, w = t >> 6;
  const int k = kg * 4 + w;
  const float* ab = agg + ((size_t)n * 64 + k) * 512 + lane * 8;
  float v[8];
#pragma unroll
  for (int j = 0; j < 8; ++j) v[j] = 0.f;
#pragma unroll
  for (int pp = 0; pp < 8; ++pp) {
    const float4* p4 = (const float4*)(ab + (size_t)pp * 32 * (K_ * D_));
    float4 r0 = p4[0], r1 = p4[1];
    v[0] += r0.x; v[1] += r0.y; v[2] += r0.z; v[3] += r0.w;
    v[4] += r1.x; v[5] += r1.y; v[6] += r1.z; v[7] += r1.w;
  }
  const float asum = a_sum[n * 64 + k];
  const float4* c4 = (const float4*)(cent + k * 512 + lane * 8);
  float4 c0 = c4[0], c1 = c4[1];
  v[0] -= asum * c0.x; v[1] -= asum * c0.y; v[2] -= asum * c0.z; v[3] -= asum * c0.w;
  v[4] -= asum * c1.x; v[5] -= asum * c1.y; v[6] -= asum * c1.z; v[7] -= asum * c1.w;
  float ssq = 0.f;
#pragma unroll
  for (int j = 0; j < 8; ++j) ssq += v[j] * v[j];
  ssq += __shfl_xor(ssq, 1);  ssq += __shfl_xor(ssq, 2);  ssq += __shfl_xor(ssq, 4);
  ssq += __shfl_xor(ssq, 8);  ssq += __shfl_xor(ssq, 16); ssq += __shfl_xor(ssq, 32);
  float4* o4 = (float4*)(out + (size_t)n * 32768 + k * 512 + lane * 8);
  o4[0] = make_float4(v[0], v[1], v[2], v[3]);
  o4[1] = make_float4(v[4], v[5], v[6], v[7]);
  if (lane == 0) rowsq[n * 64 + k] = ssq;
}

// -------- K3b: intra + global normalize (scale in place) --------
__global__ __launch_bounds__(256) void k3b_kernel(const float* __restrict__ rowsq,
                                                  float* __restrict__ out) {
  __shared__ float invr_s[64];
  __shared__ float gi_s;
  const int n = blockIdx.x >> 3;
  const int seg = blockIdx.x & 7;
  const int t = threadIdx.x;
  if (t < 64) {
    float r = rowsq[n * 64 + t];
    float ri = 1.f / fmaxf(sqrtf(r), 1e-12f);
    invr_s[t] = ri;
    float g = r * ri * ri;
    g += __shfl_xor(g, 1); g += __shfl_xor(g, 2); g += __shfl_xor(g, 4);
    g += __shfl_xor(g, 8); g += __shfl_xor(g, 16); g += __shfl_xor(g, 32);
    if (t == 0) gi_s = 1.f / fmaxf(sqrtf(g), 1e-12f);
  }
  __syncthreads();
  const int e0 = seg * 4096 + t * 16;
  const float sc = invr_s[e0 >> 9] * gi_s;
  float4* o4 = (float4*)(out + (size_t)n * 32768 + e0);
#pragma unroll
  for (int i = 0; i < 4; ++i) {
    float4 vv = o4[i];
    vv.x *= sc; vv.y *= sc; vv.z *= sc; vv.w *= sc;
    o4[i] = vv;
  }
}

extern "C" void kernel_launch(void* const* d_in, const int* in_sizes, int n_in,
                              void* d_out, int out_size, void* d_ws, size_t ws_size,
                              hipStream_t stream) {
  (void)in_sizes; (void)n_in; (void)out_size; (void)ws_size;
  const float* x    = (const float*)d_in[0];
  const float* cw   = (const float*)d_in[1];
  const float* cent = (const float*)d_in[2];
  float* out = (float*)d_out;
  char* ws = (char*)d_ws;
  u16*   wbf   = (u16*)(ws);
  float* a_sum = (float*)(ws + 65536);
  float* agg   = (float*)(ws + 73728);
  float* rowsq = (float*)(ws + 33628160);

  hipMemsetAsync(a_sum, 0, 64 * 32 * sizeof(float), stream);
  kw_kernel<<<32, 256, 0, stream>>>(cw, wbf);
  f_kernel<<<256, 256, 0, stream>>>(x, wbf, agg, a_sum);
  k3a_kernel<<<512, 256, 0, stream>>>(agg, a_sum, cent, out, rowsq);
  k3b_kernel<<<256, 256, 0, stream>>>(rowsq, out);
}